// Round 3
// baseline (516.936 us; speedup 1.0000x reference)
//
#include <hip/hip_runtime.h>
#include <stdint.h>

#define DM 768
#define VOC 32128
#define VOCP 32256          // padded to 126 x 256
#define NTOK 2048
#define NBY2 126            // vocab tiles of 256 (padded)
#define IGN (-100)

typedef __bf16 bf16x8 __attribute__((ext_vector_type(8)));
typedef float f32x4 __attribute__((ext_vector_type(4)));

typedef __attribute__((address_space(1))) void gvoid_t;
typedef __attribute__((address_space(3))) void svoid_t;

__device__ __forceinline__ void gl_lds16(const void* g, void* s) {
  // 16B per lane; LDS dest = wave-uniform base + lane*16 (linear)
  __builtin_amdgcn_global_load_lds((gvoid_t*)g, (svoid_t*)s, 16, 0, 0);
}

__device__ __forceinline__ unsigned short f2bf(float f) {
  unsigned int u = __float_as_uint(f);
  u = (u + 0x7fffu + ((u >> 16) & 1u)) >> 16;  // RNE
  return (unsigned short)u;
}

#define BAR()   asm volatile("s_barrier" ::: "memory")
#define LGKM0() asm volatile("s_waitcnt lgkmcnt(0)" ::: "memory")

// ---------------- W fp32 -> bf16 (padded: rows [VOC,VOCP) zero) ----------------
__global__ void __launch_bounds__(256) cvt_w_kernel(const float* __restrict__ W,
                                                    unsigned short* __restrict__ Wb) {
  size_t i = ((size_t)blockIdx.x * 256 + threadIdx.x) * 4;
  ushort4 o;
  if (i < (size_t)VOC * DM) {
    float4 v = *(const float4*)(W + i);
    o.x = f2bf(v.x); o.y = f2bf(v.y); o.z = f2bf(v.z); o.w = f2bf(v.w);
  } else {
    o.x = 0; o.y = 0; o.z = 0; o.w = 0;
  }
  *(ushort4*)(Wb + i) = o;
}

// ---------------- RMSNorm -> bf16 ----------------
__global__ void __launch_bounds__(256) rmsnorm_kernel(const float* __restrict__ x,
                                                      const float* __restrict__ w,
                                                      unsigned short* __restrict__ h) {
  int tok = blockIdx.x;
  const float* xr = x + (size_t)tok * DM;
  int t = threadIdx.x;
  float v0 = xr[t], v1 = xr[t + 256], v2 = xr[t + 512];
  float ss = v0 * v0 + v1 * v1 + v2 * v2;
  for (int off = 32; off; off >>= 1) ss += __shfl_down(ss, off);
  __shared__ float red[4];
  int wv = t >> 6, ln = t & 63;
  if (ln == 0) red[wv] = ss;
  __syncthreads();
  float tot = red[0] + red[1] + red[2] + red[3];
  float inv = rsqrtf(tot * (1.0f / DM) + 1e-6f);
  unsigned short* hr = h + (size_t)tok * DM;
  hr[t]       = f2bf(v0 * inv * w[t]);
  hr[t + 256] = f2bf(v1 * inv * w[t + 256]);
  hr[t + 512] = f2bf(v2 * inv * w[t + 512]);
}

// ---------------- GEMM + fused CE partials (m201 geometry) ----------------
// BM=256(tok) x BN=256(voc) x BK=64; 8 waves; per-wave 128x64 (acc 8x4).
// LDS: 2 x (A 256x64 + B 256x64) bf16 = 128KB, double-buffered per K-tile.
// Per K-tile, 4 phases:
//   ph0: ds_read b0-3,a0-3 @kk0 ; lgkm0 ; bar ; 16 MFMA (mi0-3) ; bar
//   ph1: ds_read a4-7 @kk0      ; lgkm0 ; bar ; 16 MFMA (mi4-7) ; bar
//   ph2: ds_read b0-3,a0-3 @kk1 ; lgkm0 ; bar ; 16 MFMA (mi0-3) ; bar
//   ph3: ds_read a4-7 @kk1 ; lgkm0 ; bar (all reads of buf drained)
//        STAGE tile t+2 into this buf (8 gl_lds) ; 16 MFMA (mi4-7)
//        vmcnt(8)  [tile t+1 landed; t+2's 8 still flying] ; bar
// Raw asm s_barrier (no vmcnt(0) drain) + "memory" clobber pins ordering.
// LDS swizzle (both-sides, rule #21): slot q at row r stored at q^(r&7);
// gl_lds source col pre-swizzled, ds_read applies same XOR. 0 conflicts.
#define BUF_ELEMS 32768     // A 16384 + B 16384
#define B_OFF     16384

__global__ void __launch_bounds__(512, 2) gemm_kernel(const unsigned short* __restrict__ A,
                                                      const unsigned short* __restrict__ Bw,
                                                      float* __restrict__ C,
                                                      float* __restrict__ Pm,
                                                      float* __restrict__ Ps) {
  __shared__ __align__(16) unsigned short LDS[2 * BUF_ELEMS];

  // XCD grouping: 1008 blocks = 8 xcd x 126. Within an XCD, consecutive w
  // share one n-panel across the 8 m-tiles -> W panel stays in that XCD's L2.
  const int id  = blockIdx.x;
  const int w   = (id & 7) * 126 + (id >> 3);  // bijective for 1008
  const int nt  = w >> 3;                      // 0..125 vocab tile (256 wide)
  const int m0  = (w & 7) * 256;               // token offset
  const int n0  = nt * 256;                    // (padded) vocab offset

  const int tid  = threadIdx.x;
  const int wv   = tid >> 6, ln = tid & 63;
  const int l15  = ln & 15, quad = ln >> 4;
  const int wvm  = wv >> 2;                    // 0..1 -> 128-row slice
  const int wvn  = wv & 3;                     // 0..3 -> 64-col slice
  const int sw   = l15 & 7;

  // staging: wave wv stages A rows [wv*32,+32) and B rows [wv*32,+32)
  const int lr  = ln >> 3;                     // row within 8-row chunk
  const int qsw = ((ln & 7) ^ lr) * 8;         // pre-swizzled source k-slot
  const unsigned short* aS = A  + (size_t)(m0 + wv * 32 + lr) * DM + qsw;
  const unsigned short* bS = Bw + (size_t)(n0 + wv * 32 + lr) * DM + qsw;
  const int aDof = wv * 32 * 64;
  const int bDof = B_OFF + wv * 32 * 64;

  auto STAGE = [&](unsigned short* sb, int kt) {
    const unsigned short* a = aS + kt * 64;
    const unsigned short* b = bS + kt * 64;
    unsigned short* ad = sb + aDof;
    unsigned short* bd = sb + bDof;
#pragma unroll
    for (int c = 0; c < 4; ++c) {
      gl_lds16(a + (size_t)c * (8 * DM), ad + c * 512);
      gl_lds16(b + (size_t)c * (8 * DM), bd + c * 512);
    }
  };

  f32x4 acc[8][4];
#pragma unroll
  for (int i = 0; i < 8; ++i)
#pragma unroll
    for (int j = 0; j < 4; ++j) {
      acc[i][j][0] = 0.f; acc[i][j][1] = 0.f; acc[i][j][2] = 0.f; acc[i][j][3] = 0.f;
    }

  bf16x8 a[4], b[4];
  auto LDA4 = [&](const unsigned short* Ap, int mibase, int kk) {
    const int so = (((kk << 2) + quad) ^ sw) * 8;
#pragma unroll
    for (int i = 0; i < 4; ++i)
      a[i] = *(const bf16x8*)(Ap + (wvm * 128 + (mibase + i) * 16 + l15) * 64 + so);
  };
  auto LDB4 = [&](const unsigned short* Bp, int kk) {
    const int so = (((kk << 2) + quad) ^ sw) * 8;
#pragma unroll
    for (int i = 0; i < 4; ++i)
      b[i] = *(const bf16x8*)(Bp + (wvn * 64 + i * 16 + l15) * 64 + so);
  };
  auto MM16 = [&](int mibase) {
    __builtin_amdgcn_s_setprio(1);
#pragma unroll
    for (int i = 0; i < 4; ++i)
#pragma unroll
      for (int j = 0; j < 4; ++j)
        acc[mibase + i][j] =
            __builtin_amdgcn_mfma_f32_16x16x32_bf16(a[i], b[j], acc[mibase + i][j], 0, 0, 0);
    __builtin_amdgcn_s_setprio(0);
  };

  unsigned short* pc = LDS;
  unsigned short* po = LDS + BUF_ELEMS;

  STAGE(pc, 0); STAGE(po, 1);                  // 16 outstanding
  asm volatile("s_waitcnt vmcnt(8)" ::: "memory");   // tile0 landed
  BAR();

  for (int t = 0; t < 12; ++t) {               // K = 768 -> 12 tiles of 64
    const unsigned short* Ap = pc;
    const unsigned short* Bp = pc + B_OFF;
    // ph0
    LDB4(Bp, 0); LDA4(Ap, 0, 0);
    LGKM0(); BAR();
    MM16(0);
    BAR();
    // ph1
    LDA4(Ap, 4, 0);
    LGKM0(); BAR();
    MM16(4);
    BAR();
    // ph2
    LDB4(Bp, 1); LDA4(Ap, 0, 1);
    LGKM0(); BAR();
    MM16(0);
    BAR();
    // ph3
    LDA4(Ap, 4, 1);
    LGKM0(); BAR();                            // all waves' reads of pc drained
    if (t <= 9) STAGE(pc, t + 2);              // overwrite pc; loads fly over MFMA
    MM16(4);
    if (t <= 9)       { asm volatile("s_waitcnt vmcnt(8)" ::: "memory"); }
    else if (t == 10) { asm volatile("s_waitcnt vmcnt(0)" ::: "memory"); }
    BAR();
    unsigned short* tmp = pc; pc = po; po = tmp;
  }

  // column-group validity (padded tail tile): 16-aligned, wave-uniform
  bool vn[4];
#pragma unroll
  for (int ni = 0; ni < 4; ++ni) vn[ni] = (n0 + wvn * 64 + ni * 16) < VOC;

  // ---- Epilogue 1: non-temporal score stores (col = l15 + ni*16, row = quad*4+r).
  if (n0 + 256 <= VOC) {
#pragma unroll
    for (int mi = 0; mi < 8; ++mi) {
#pragma unroll
      for (int r = 0; r < 4; ++r) {
        const int row = m0 + wvm * 128 + mi * 16 + quad * 4 + r;
        float* cp = C + (size_t)row * VOC + (n0 + wvn * 64 + l15);
#pragma unroll
        for (int ni = 0; ni < 4; ++ni)
          __builtin_nontemporal_store(acc[mi][ni][r], cp + ni * 16);
      }
    }
  } else {
#pragma unroll
    for (int mi = 0; mi < 8; ++mi) {
#pragma unroll
      for (int r = 0; r < 4; ++r) {
        const int row = m0 + wvm * 128 + mi * 16 + quad * 4 + r;
        float* cp = C + (size_t)row * VOC + (n0 + wvn * 64 + l15);
#pragma unroll
        for (int ni = 0; ni < 4; ++ni)
          if (vn[ni]) __builtin_nontemporal_store(acc[mi][ni][r], cp + ni * 16);
      }
    }
  }

  // ---- Epilogue 2: per-row (max,sumexp) over this block's 256 cols.
  // Each wave: 64 cols -> in-lane over valid ni, then 16-lane shfl_xor reduce.
  float* pmL = (float*)LDS;        // [4 wvn][256 rows]
  float* psL = pmL + 1024;
#pragma unroll
  for (int mi = 0; mi < 8; ++mi) {
#pragma unroll
    for (int r = 0; r < 4; ++r) {
      float m = -3.0e38f;
#pragma unroll
      for (int ni = 0; ni < 4; ++ni)
        if (vn[ni]) m = fmaxf(m, acc[mi][ni][r]);
#pragma unroll
      for (int off = 1; off < 16; off <<= 1) m = fmaxf(m, __shfl_xor(m, off));
      float s = 0.f;
#pragma unroll
      for (int ni = 0; ni < 4; ++ni)
        if (vn[ni]) s += __expf(acc[mi][ni][r] - m);
#pragma unroll
      for (int off = 1; off < 16; off <<= 1) s += __shfl_xor(s, off);
      if (l15 == 0) {
        int rr = wvm * 128 + mi * 16 + quad * 4 + r;   // 0..255
        pmL[wvn * 256 + rr] = m;
        psL[wvn * 256 + rr] = s;
      }
    }
  }
  LGKM0(); BAR();
  if (tid < 256) {
    float ma = pmL[tid], mb = pmL[256 + tid], mc = pmL[512 + tid], md = pmL[768 + tid];
    float M = fmaxf(fmaxf(ma, mb), fmaxf(mc, md));
    float S = psL[tid] * __expf(ma - M) + psL[256 + tid] * __expf(mb - M) +
              psL[512 + tid] * __expf(mc - M) + psL[768 + tid] * __expf(md - M);
    Pm[(size_t)nt * NTOK + m0 + tid] = M;    // coalesced: [nt][token]
    Ps[(size_t)nt * NTOK + m0 + tid] = S;
  }
}

// ---------------- combine 126 partials per token ----------------
__global__ void __launch_bounds__(256) loss_finalize_kernel(const float* __restrict__ Pm,
                                                            const float* __restrict__ Ps,
                                                            const float* __restrict__ scores,
                                                            const int* __restrict__ labels,
                                                            float* __restrict__ nll) {
  const int tok = blockIdx.x;
  float m = -1e30f, s = 0.f;
  for (int j = threadIdx.x; j < NBY2; j += 256) {
    float m2 = Pm[(size_t)j * NTOK + tok], s2 = Ps[(size_t)j * NTOK + tok];
    float nm = fmaxf(m, m2);
    s = s * __expf(m - nm) + s2 * __expf(m2 - nm);
    m = nm;
  }
  for (int off = 32; off; off >>= 1) {
    float m2 = __shfl_down(m, off), s2 = __shfl_down(s, off);
    float nm = fmaxf(m, m2);
    s = s * __expf(m - nm) + s2 * __expf(m2 - nm);
    m = nm;
  }
  __shared__ float ms[4], sh[4];
  int wv = threadIdx.x >> 6, ln = threadIdx.x & 63;
  if (ln == 0) { ms[wv] = m; sh[wv] = s; }
  __syncthreads();
  if (threadIdx.x == 0) {
    float M = ms[0], S = sh[0];
    for (int i = 1; i < 4; ++i) {
      float nm = fmaxf(M, ms[i]);
      S = S * __expf(M - nm) + sh[i] * __expf(ms[i] - nm);
      M = nm;
    }
    int lab = labels[tok];
    float v = 0.f;
    if (lab != IGN) v = (M + logf(S)) - scores[(size_t)tok * VOC + lab];
    nll[tok] = v;
  }
}

__global__ void __launch_bounds__(256) reduce_kernel(const float* __restrict__ nll,
                                                     const int* __restrict__ labels,
                                                     float* __restrict__ out) {
  float s = 0.f, c = 0.f;
  for (int i = threadIdx.x; i < NTOK; i += 256) {
    s += nll[i];
    c += (labels[i] != IGN) ? 1.0f : 0.0f;
  }
  for (int off = 32; off; off >>= 1) { s += __shfl_down(s, off); c += __shfl_down(c, off); }
  __shared__ float rs[4], rc[4];
  int wv = threadIdx.x >> 6, ln = threadIdx.x & 63;
  if (ln == 0) { rs[wv] = s; rc[wv] = c; }
  __syncthreads();
  if (threadIdx.x == 0) {
    float S = rs[0] + rs[1] + rs[2] + rs[3];
    float Cc = rc[0] + rc[1] + rc[2] + rc[3];
    out[0] = S / fmaxf(Cc, 1.0f);
  }
}

extern "C" void kernel_launch(void* const* d_in, const int* in_sizes, int n_in,
                              void* d_out, int out_size, void* d_ws, size_t ws_size,
                              hipStream_t stream) {
  const float* hs     = (const float*)d_in[0];  // [4,512,768] f32
  const int*   labels = (const int*)d_in[1];    // [4,512] i32
  const float* lnw    = (const float*)d_in[2];  // [768] f32
  const float* W      = (const float*)d_in[3];  // [32128,768] f32

  float* out    = (float*)d_out;
  float* scores = out + 1;                      // [2048,32128] f32

  char* ws = (char*)d_ws;
  unsigned short* Wb = (unsigned short*)ws;                 ws += (size_t)VOCP * DM * 2;   // 49.5 MB
  unsigned short* Hb = (unsigned short*)ws;                 ws += (size_t)NTOK * DM * 2;   // 3.1 MB
  float* Pm          = (float*)ws;                          ws += (size_t)NBY2 * NTOK * 4; // 1.03 MB
  float* Ps          = (float*)ws;                          ws += (size_t)NBY2 * NTOK * 4; // 1.03 MB
  float* nll         = (float*)ws;

  cvt_w_kernel<<<(VOCP * DM / 4) / 256, 256, 0, stream>>>(W, Wb);
  rmsnorm_kernel<<<NTOK, 256, 0, stream>>>(hs, lnw, Hb);
  gemm_kernel<<<8 * NBY2, 512, 0, stream>>>(Hb, Wb, scores, Pm, Ps);
  loss_finalize_kernel<<<NTOK, 256, 0, stream>>>(Pm, Ps, scores, labels, nll);
  reduce_kernel<<<1, 256, 0, stream>>>(nll, labels, out);
}